// Round 1
// baseline (847.472 us; speedup 1.0000x reference)
//
#include <hip/hip_runtime.h>
#include <hip/hip_bf16.h>

typedef __attribute__((ext_vector_type(8))) short bf16x8;
typedef __attribute__((ext_vector_type(4))) unsigned short u16x4;
typedef __attribute__((ext_vector_type(4))) float f32x4;

constexpr int Bb = 4, Tt = 2048, Dd = 2048, Hh = 16, DHd = 128;

static __device__ __forceinline__ unsigned short f2bf(float f) {
  union { float f; unsigned u; } x; x.f = f;
  unsigned r = x.u + 0x7fffu + ((x.u >> 16) & 1u);
  return (unsigned short)(r >> 16);
}

// ---------------------------------------------------------------------------
// Weight transpose + fp32->bf16 convert: W[k][n] -> Wt[n][k]
// ---------------------------------------------------------------------------
__global__ __launch_bounds__(256) void wtrans_all(
    const float* __restrict__ Wq, const float* __restrict__ Wk,
    const float* __restrict__ Wv, const float* __restrict__ Wo,
    unsigned short* __restrict__ WqT, unsigned short* __restrict__ WkT,
    unsigned short* __restrict__ WvT, unsigned short* __restrict__ WoT,
    float qscale) {
  __shared__ __align__(16) unsigned short tile[64][72];
  const float* src;
  unsigned short* dst;
  float sc = 1.0f;
  switch (blockIdx.z) {
    case 0: src = Wq; dst = WqT; sc = qscale; break;
    case 1: src = Wk; dst = WkT; break;
    case 2: src = Wv; dst = WvT; break;
    default: src = Wo; dst = WoT; break;
  }
  const int t = threadIdx.x;
  const int k0 = blockIdx.x * 64, n0 = blockIdx.y * 64;
  const int c = t & 15, r = t >> 4;
#pragma unroll
  for (int p = 0; p < 4; ++p) {
    const int rr = r + 16 * p;
    float4 v = *(const float4*)(src + (size_t)(k0 + rr) * Dd + n0 + c * 4);
    u16x4 pk;
    pk[0] = f2bf(v.x * sc); pk[1] = f2bf(v.y * sc);
    pk[2] = f2bf(v.z * sc); pk[3] = f2bf(v.w * sc);
    *(u16x4*)&tile[rr][c * 4] = pk;
  }
  __syncthreads();
#pragma unroll
  for (int p = 0; p < 4; ++p) {
    const int nn = r + 16 * p;
    u16x4 pk;
    pk[0] = tile[c * 4 + 0][nn]; pk[1] = tile[c * 4 + 1][nn];
    pk[2] = tile[c * 4 + 2][nn]; pk[3] = tile[c * 4 + 3][nn];
    *(u16x4*)(dst + (size_t)(n0 + nn) * Dd + k0 + c * 4) = pk;
  }
}

// ---------------------------------------------------------------------------
// GEMM: out[M=8192][N=2048] = A[M][K=2048] * Bt[N][K]^T  (bf16 MFMA, f32 acc)
// AMODE: 0 = A fp32 (convert on stage), 1 = A bf16
// OMODE: 0 = fp32 flat [M][N]; 1 = bf16 split [B,H,T,dh]; 2 = bf16 [B,H,dh,T]
// 128x128 tile, BK=64, 4 waves (2x2), each wave 64x64 = 4x4 of 16x16x32.
// ---------------------------------------------------------------------------
template <int AMODE, int OMODE>
__global__ __launch_bounds__(256, 2) void gemm_bt(
    const void* __restrict__ Ap, const unsigned short* __restrict__ Bt,
    void* __restrict__ Outp) {
  __shared__ __align__(16) unsigned short As[128][72];  // stride 144B: b128 reads ~2-way
  __shared__ __align__(16) unsigned short Bs[128][72];
  const int t = threadIdx.x;
  const int lane = t & 63, w = t >> 6;
  const int wr = w >> 1, wc = w & 1;
  const int fr = lane & 15, fq = lane >> 4;
  const int m0 = blockIdx.x * 128, n0 = blockIdx.y * 128;
  const int c8 = t & 7, r8 = t >> 3;  // 8 x 16B chunks per 64-wide row

  f32x4 acc[4][4] = {};

  for (int k0 = 0; k0 < Dd; k0 += 64) {
    if (AMODE == 0) {
      const float* A = (const float*)Ap;
#pragma unroll
      for (int p = 0; p < 4; ++p) {
        const int row = r8 + 32 * p;
        const float* s0 = A + (size_t)(m0 + row) * Dd + k0 + c8 * 8;
        float4 v0 = *(const float4*)(s0);
        float4 v1 = *(const float4*)(s0 + 4);
        bf16x8 pk;
        pk[0] = (short)f2bf(v0.x); pk[1] = (short)f2bf(v0.y);
        pk[2] = (short)f2bf(v0.z); pk[3] = (short)f2bf(v0.w);
        pk[4] = (short)f2bf(v1.x); pk[5] = (short)f2bf(v1.y);
        pk[6] = (short)f2bf(v1.z); pk[7] = (short)f2bf(v1.w);
        *(bf16x8*)&As[row][c8 * 8] = pk;
      }
    } else {
      const unsigned short* A = (const unsigned short*)Ap;
#pragma unroll
      for (int p = 0; p < 4; ++p) {
        const int row = r8 + 32 * p;
        *(bf16x8*)&As[row][c8 * 8] =
            *(const bf16x8*)(A + (size_t)(m0 + row) * Dd + k0 + c8 * 8);
      }
    }
#pragma unroll
    for (int p = 0; p < 4; ++p) {
      const int row = r8 + 32 * p;
      *(bf16x8*)&Bs[row][c8 * 8] =
          *(const bf16x8*)(Bt + (size_t)(n0 + row) * Dd + k0 + c8 * 8);
    }
    __syncthreads();
#pragma unroll
    for (int ks = 0; ks < 2; ++ks) {
      bf16x8 af[4], bfr[4];
#pragma unroll
      for (int m = 0; m < 4; ++m)
        af[m] = *(const bf16x8*)&As[wr * 64 + m * 16 + fr][ks * 32 + fq * 8];
#pragma unroll
      for (int n = 0; n < 4; ++n)
        bfr[n] = *(const bf16x8*)&Bs[wc * 64 + n * 16 + fr][ks * 32 + fq * 8];
#pragma unroll
      for (int m = 0; m < 4; ++m)
#pragma unroll
        for (int n = 0; n < 4; ++n)
          acc[m][n] = __builtin_amdgcn_mfma_f32_16x16x32_bf16(
              af[m], bfr[n], acc[m][n], 0, 0, 0);
    }
    __syncthreads();
  }

#pragma unroll
  for (int m = 0; m < 4; ++m) {
    const int mg = m0 + wr * 64 + m * 16 + fq * 4;
    const int bb = mg >> 11, tt0 = mg & (Tt - 1);
#pragma unroll
    for (int n = 0; n < 4; ++n) {
      const int ng = n0 + wc * 64 + n * 16 + fr;
      if (OMODE == 0) {
        float* o = (float*)Outp + (size_t)mg * Dd + ng;
#pragma unroll
        for (int r = 0; r < 4; ++r) o[(size_t)r * Dd] = acc[m][n][r];
      } else if (OMODE == 1) {
        const int h = ng >> 7, dh = ng & 127;
        unsigned short* o = (unsigned short*)Outp +
                            (((size_t)bb * Hh + h) * Tt + tt0) * DHd + dh;
#pragma unroll
        for (int r = 0; r < 4; ++r) o[r * DHd] = f2bf(acc[m][n][r]);
      } else {
        const int h = ng >> 7, dh = ng & 127;
        u16x4 pk;
#pragma unroll
        for (int r = 0; r < 4; ++r) pk[r] = f2bf(acc[m][n][r]);
        *(u16x4*)((unsigned short*)Outp +
                  (((size_t)bb * Hh + h) * DHd + dh) * Tt + tt0) = pk;
      }
    }
  }
}

// ---------------------------------------------------------------------------
// Causal flash attention. Q,K: [B,H,T,dh] bf16; V: [B,H,dh,T] bf16 (transposed)
// Out: [B,T,H*dh] bf16. QBLK=64 (4 waves x 16 rows), KVBLK=64.
// Scale 1/sqrt(dh) is pre-folded into Wq.
// ---------------------------------------------------------------------------
__global__ __launch_bounds__(256, 2) void fattn(
    const unsigned short* __restrict__ Qp, const unsigned short* __restrict__ Kp,
    const unsigned short* __restrict__ Vt, unsigned short* __restrict__ Ao) {
  __shared__ __align__(16) unsigned short Ks[64][136];   // [kv][k], 272B stride
  __shared__ __align__(16) unsigned short Vs[128][72];   // [dv][kv], 144B stride
  __shared__ __align__(16) unsigned short Ps[4][16][72]; // per-wave P roundtrip
  const int t = threadIdx.x, lane = t & 63, w = t >> 6;
  const int fr = lane & 15, fq = lane >> 4;
  const int q0 = blockIdx.x * 64;
  const int bh = blockIdx.y;
  const unsigned short* Qb = Qp + (size_t)bh * Tt * DHd;
  const unsigned short* Kb = Kp + (size_t)bh * Tt * DHd;
  const unsigned short* Vb = Vt + (size_t)bh * DHd * Tt;

  bf16x8 qf[4];
#pragma unroll
  for (int ks = 0; ks < 4; ++ks)
    qf[ks] = *(const bf16x8*)(Qb + (size_t)(q0 + 16 * w + fr) * DHd + ks * 32 + fq * 8);

  f32x4 oacc[8] = {};
  float mrow[4] = {-1e30f, -1e30f, -1e30f, -1e30f};
  float lrow[4] = {0.f, 0.f, 0.f, 0.f};

  const int ntile = blockIdx.x + 1;
  for (int kt = 0; kt < ntile; ++kt) {
    const int kv0 = kt * 64;
    __syncthreads();  // protect LDS vs previous iteration's reads
    {
      const int ck = t & 15, rk = t >> 4;
#pragma unroll
      for (int p = 0; p < 4; ++p) {
        const int row = rk + 16 * p;
        *(bf16x8*)&Ks[row][ck * 8] =
            *(const bf16x8*)(Kb + (size_t)(kv0 + row) * DHd + ck * 8);
      }
      const int cv = t & 7, rv = t >> 3;
#pragma unroll
      for (int p = 0; p < 4; ++p) {
        const int row = rv + 32 * p;
        *(bf16x8*)&Vs[row][cv * 8] =
            *(const bf16x8*)(Vb + (size_t)row * Tt + kv0 + cv * 8);
      }
    }
    __syncthreads();

    // S = Q K^T  (D-layout: col=fr -> kv, row=fq*4+r -> q-row)
    f32x4 s[4] = {};
#pragma unroll
    for (int tt = 0; tt < 4; ++tt)
#pragma unroll
      for (int ks = 0; ks < 4; ++ks) {
        bf16x8 kf = *(const bf16x8*)&Ks[tt * 16 + fr][ks * 32 + fq * 8];
        s[tt] = __builtin_amdgcn_mfma_f32_16x16x32_bf16(qf[ks], kf, s[tt], 0, 0, 0);
      }

    if (kv0 == q0) {  // diagonal tile: causal mask (earlier tiles fully valid)
#pragma unroll
      for (int tt = 0; tt < 4; ++tt)
#pragma unroll
        for (int r = 0; r < 4; ++r)
          if (tt * 16 + fr > 16 * w + fq * 4 + r) s[tt][r] = -1e30f;
    }

    // wave-parallel online softmax (16-lane-group shuffle reduce)
    float tm[4], al[4], rs[4];
#pragma unroll
    for (int r = 0; r < 4; ++r)
      tm[r] = fmaxf(fmaxf(s[0][r], s[1][r]), fmaxf(s[2][r], s[3][r]));
#pragma unroll
    for (int d = 1; d < 16; d <<= 1)
#pragma unroll
      for (int r = 0; r < 4; ++r) tm[r] = fmaxf(tm[r], __shfl_xor(tm[r], d));
#pragma unroll
    for (int r = 0; r < 4; ++r) {
      const float mn = fmaxf(mrow[r], tm[r]);
      al[r] = __expf(mrow[r] - mn);
      mrow[r] = mn;
      rs[r] = 0.f;
    }
#pragma unroll
    for (int tt = 0; tt < 4; ++tt)
#pragma unroll
      for (int r = 0; r < 4; ++r) {
        const float p = __expf(s[tt][r] - mrow[r]);
        s[tt][r] = p;
        rs[r] += p;
      }
#pragma unroll
    for (int d = 1; d < 16; d <<= 1)
#pragma unroll
      for (int r = 0; r < 4; ++r) rs[r] += __shfl_xor(rs[r], d);
#pragma unroll
    for (int r = 0; r < 4; ++r) lrow[r] = lrow[r] * al[r] + rs[r];
#pragma unroll
    for (int dt = 0; dt < 8; ++dt)
#pragma unroll
      for (int r = 0; r < 4; ++r) oacc[dt][r] *= al[r];

    // P -> LDS (S-layout write) -> A-fragment read
#pragma unroll
    for (int tt = 0; tt < 4; ++tt)
#pragma unroll
      for (int r = 0; r < 4; ++r)
        Ps[w][fq * 4 + r][tt * 16 + fr] = f2bf(s[tt][r]);
    __syncthreads();

#pragma unroll
    for (int ks2 = 0; ks2 < 2; ++ks2) {
      const bf16x8 pf = *(const bf16x8*)&Ps[w][fr][ks2 * 32 + fq * 8];
#pragma unroll
      for (int dt = 0; dt < 8; ++dt) {
        const bf16x8 vf = *(const bf16x8*)&Vs[dt * 16 + fr][ks2 * 32 + fq * 8];
        oacc[dt] = __builtin_amdgcn_mfma_f32_16x16x32_bf16(pf, vf, oacc[dt], 0, 0, 0);
      }
    }
  }

  const int bb = bh >> 4, hh = bh & 15;
  const int tg = q0 + 16 * w + fq * 4;
#pragma unroll
  for (int r = 0; r < 4; ++r) {
    const float invl = 1.0f / lrow[r];
    unsigned short* o = Ao + ((size_t)bb * Tt + tg + r) * Dd + hh * DHd + fr;
#pragma unroll
    for (int dt = 0; dt < 8; ++dt) o[dt * 16] = f2bf(oacc[dt][r] * invl);
  }
}

// ---------------------------------------------------------------------------
extern "C" void kernel_launch(void* const* d_in, const int* in_sizes, int n_in,
                              void* d_out, int out_size, void* d_ws, size_t ws_size,
                              hipStream_t stream) {
  const float* q = (const float*)d_in[0];
  const float* k = (const float*)d_in[1];
  const float* v = (const float*)d_in[2];
  // d_in[3] = mask (known causal tril; unused)
  const float* Wq = (const float*)d_in[4];
  const float* Wk = (const float*)d_in[5];
  const float* Wv = (const float*)d_in[6];
  const float* Wo = (const float*)d_in[7];

  const size_t WE = (size_t)Dd * Dd;            // 4.19M elems (8.4 MB bf16)
  const size_t PE = (size_t)Bb * Hh * Tt * DHd; // 16.78M elems (33.5 MB bf16)
  unsigned short* WqT = (unsigned short*)d_ws;
  unsigned short* WkT = WqT + WE;
  unsigned short* WvT = WkT + WE;
  unsigned short* WoT = WvT + WE;
  unsigned short* Qx = WoT + WE;  // [B,H,T,dh]
  unsigned short* Kx = Qx + PE;   // [B,H,T,dh]
  unsigned short* Vx = Kx + PE;   // [B,H,dh,T]
  unsigned short* Ax = Vx + PE;   // [B,T,H*dh]

  wtrans_all<<<dim3(32, 32, 4), 256, 0, stream>>>(
      Wq, Wk, Wv, Wo, WqT, WkT, WvT, WoT, 0.088388347648318447f);
  gemm_bt<0, 1><<<dim3(64, 16), 256, 0, stream>>>(q, WqT, Qx);
  gemm_bt<0, 1><<<dim3(64, 16), 256, 0, stream>>>(k, WkT, Kx);
  gemm_bt<0, 2><<<dim3(64, 16), 256, 0, stream>>>(v, WvT, Vx);
  fattn<<<dim3(Tt / 64, Bb * Hh), 256, 0, stream>>>(Qx, Kx, Vx, Ax);
  gemm_bt<1, 0><<<dim3(64, 16), 256, 0, stream>>>(Ax, WoT, (float*)d_out);
}

// Round 2
// 738.766 us; speedup vs baseline: 1.1471x; 1.1471x over previous
//
#include <hip/hip_runtime.h>
#include <hip/hip_bf16.h>

typedef __attribute__((ext_vector_type(8))) short bf16x8;
typedef __attribute__((ext_vector_type(4))) unsigned short u16x4;
typedef __attribute__((ext_vector_type(4))) float f32x4;

constexpr int Bb = 4, Tt = 2048, Dd = 2048, Hh = 16, DHd = 128;

static __device__ __forceinline__ unsigned short f2bf(float f) {
  union { float f; unsigned u; } x; x.f = f;
  unsigned r = x.u + 0x7fffu + ((x.u >> 16) & 1u);
  return (unsigned short)(r >> 16);
}

// async global->LDS, 16B per lane (dest = wave-uniform base + lane*16)
static __device__ __forceinline__ void gld16(const void* g, void* l) {
  __builtin_amdgcn_global_load_lds(
      (__attribute__((address_space(1))) void*)g,
      (__attribute__((address_space(3))) void*)l, 16, 0, 0);
}

// ---------------------------------------------------------------------------
// fp32 -> bf16 bulk convert (8 elems/thread)
// ---------------------------------------------------------------------------
__global__ __launch_bounds__(256) void cvt_bf16(const float* __restrict__ s,
                                                unsigned short* __restrict__ d) {
  const size_t i = ((size_t)blockIdx.x * 256 + threadIdx.x) * 8;
  float4 a = *(const float4*)(s + i);
  float4 b = *(const float4*)(s + i + 4);
  bf16x8 pk;
  pk[0] = (short)f2bf(a.x); pk[1] = (short)f2bf(a.y);
  pk[2] = (short)f2bf(a.z); pk[3] = (short)f2bf(a.w);
  pk[4] = (short)f2bf(b.x); pk[5] = (short)f2bf(b.y);
  pk[6] = (short)f2bf(b.z); pk[7] = (short)f2bf(b.w);
  *(bf16x8*)(d + i) = pk;
}

// ---------------------------------------------------------------------------
// Weight transpose + fp32->bf16 convert: W[k][n] -> Wt[n][k]
// ---------------------------------------------------------------------------
__global__ __launch_bounds__(256) void wtrans_all(
    const float* __restrict__ Wq, const float* __restrict__ Wk,
    const float* __restrict__ Wv, const float* __restrict__ Wo,
    unsigned short* __restrict__ WqT, unsigned short* __restrict__ WkT,
    unsigned short* __restrict__ WvT, unsigned short* __restrict__ WoT,
    float qscale) {
  __shared__ __align__(16) unsigned short tile[64][72];
  const float* src;
  unsigned short* dst;
  float sc = 1.0f;
  switch (blockIdx.z) {
    case 0: src = Wq; dst = WqT; sc = qscale; break;
    case 1: src = Wk; dst = WkT; break;
    case 2: src = Wv; dst = WvT; break;
    default: src = Wo; dst = WoT; break;
  }
  const int t = threadIdx.x;
  const int k0 = blockIdx.x * 64, n0 = blockIdx.y * 64;
  const int c = t & 15, r = t >> 4;
#pragma unroll
  for (int p = 0; p < 4; ++p) {
    const int rr = r + 16 * p;
    float4 v = *(const float4*)(src + (size_t)(k0 + rr) * Dd + n0 + c * 4);
    u16x4 pk;
    pk[0] = f2bf(v.x * sc); pk[1] = f2bf(v.y * sc);
    pk[2] = f2bf(v.z * sc); pk[3] = f2bf(v.w * sc);
    *(u16x4*)&tile[rr][c * 4] = pk;
  }
  __syncthreads();
#pragma unroll
  for (int p = 0; p < 4; ++p) {
    const int nn = r + 16 * p;
    u16x4 pk;
    pk[0] = tile[c * 4 + 0][nn]; pk[1] = tile[c * 4 + 1][nn];
    pk[2] = tile[c * 4 + 2][nn]; pk[3] = tile[c * 4 + 3][nn];
    *(u16x4*)(dst + (size_t)(n0 + nn) * Dd + k0 + c * 4) = pk;
  }
}

// ---------------------------------------------------------------------------
// GEMM: out[8192][2048] = A[8192][2048](bf16) * Bt[2048][2048]^T (bf16)
// m97 structure: 128x128 tile, BK=64, global_load_lds width-16, linear LDS.
// OMODE: 0 = fp32 flat [M][N]; 1 = bf16 [B,H,T,dh]; 2 = bf16 [B,H,dh,T]
// ---------------------------------------------------------------------------
template <int OMODE>
__global__ __launch_bounds__(256, 2) void gemm_bt(
    const unsigned short* __restrict__ A, const unsigned short* __restrict__ Bt,
    void* __restrict__ Outp) {
  __shared__ __align__(16) unsigned short As[128 * 64];
  __shared__ __align__(16) unsigned short Bs[128 * 64];
  const int t = threadIdx.x;
  const int lane = t & 63, w = t >> 6;
  const int wr = w >> 1, wc = w & 1;
  const int fr = lane & 15, fq = lane >> 4;
  const int m0 = blockIdx.x * 128, n0 = blockIdx.y * 128;
  const int srow = t >> 3, scol = (t & 7) * 8;  // staging: 8x16B chunks per 64-col row
  const unsigned short* Ag = A + (size_t)(m0 + srow) * Dd + scol;
  const unsigned short* Bg = Bt + (size_t)(n0 + srow) * Dd + scol;
  unsigned short* Asl = As + t * 8;
  unsigned short* Bsl = Bs + t * 8;

  f32x4 acc[4][4] = {};

  for (int k0 = 0; k0 < Dd; k0 += 64) {
#pragma unroll
    for (int i = 0; i < 4; ++i) {
      gld16(Ag + (size_t)i * 32 * Dd + k0, Asl + i * 2048);
      gld16(Bg + (size_t)i * 32 * Dd + k0, Bsl + i * 2048);
    }
    __syncthreads();
#pragma unroll
    for (int ks = 0; ks < 2; ++ks) {
      bf16x8 af[4], bfr[4];
#pragma unroll
      for (int m = 0; m < 4; ++m)
        af[m] = *(const bf16x8*)&As[(wr * 64 + m * 16 + fr) * 64 + ks * 32 + fq * 8];
#pragma unroll
      for (int n = 0; n < 4; ++n)
        bfr[n] = *(const bf16x8*)&Bs[(wc * 64 + n * 16 + fr) * 64 + ks * 32 + fq * 8];
#pragma unroll
      for (int m = 0; m < 4; ++m)
#pragma unroll
        for (int n = 0; n < 4; ++n)
          acc[m][n] = __builtin_amdgcn_mfma_f32_16x16x32_bf16(
              af[m], bfr[n], acc[m][n], 0, 0, 0);
    }
    __syncthreads();
  }

#pragma unroll
  for (int m = 0; m < 4; ++m) {
    const int mg = m0 + wr * 64 + m * 16 + fq * 4;
    const int bb = mg >> 11, tt0 = mg & (Tt - 1);
#pragma unroll
    for (int n = 0; n < 4; ++n) {
      const int ng = n0 + wc * 64 + n * 16 + fr;
      if (OMODE == 0) {
        float* o = (float*)Outp + (size_t)mg * Dd + ng;
#pragma unroll
        for (int r = 0; r < 4; ++r) o[(size_t)r * Dd] = acc[m][n][r];
      } else if (OMODE == 1) {
        const int h = ng >> 7, dh = ng & 127;
        unsigned short* o = (unsigned short*)Outp +
                            (((size_t)bb * Hh + h) * Tt + tt0) * DHd + dh;
#pragma unroll
        for (int r = 0; r < 4; ++r) o[r * DHd] = f2bf(acc[m][n][r]);
      } else {
        const int h = ng >> 7, dh = ng & 127;
        u16x4 pk;
#pragma unroll
        for (int r = 0; r < 4; ++r) pk[r] = f2bf(acc[m][n][r]);
        *(u16x4*)((unsigned short*)Outp +
                  (((size_t)bb * Hh + h) * DHd + dh) * Tt + tt0) = pk;
      }
    }
  }
}

// ---------------------------------------------------------------------------
// Causal flash attention, S^T ("swapped QK") layout.
// Q,K: [B,H,T,128] bf16; V: [B,H,128,T] bf16 (transposed); Out: [B,T,2048] bf16
// QBLK=128 (4 waves x 32 q-rows, two 16-row groups), KVBLK=64.
// S^T = mfma(K-frag, Q-frag): lane holds S[kv=tt*16+fq*4+r][q=fr] ->
// softmax state is per-lane scalar; P^T packs to u16x4 LDS writes.
// ---------------------------------------------------------------------------
__global__ __launch_bounds__(256, 2) void fattn(
    const unsigned short* __restrict__ Qp, const unsigned short* __restrict__ Kp,
    const unsigned short* __restrict__ Vt, unsigned short* __restrict__ Ao) {
  __shared__ __align__(16) unsigned short Ks[64][136];   // K[kv][dh]
  __shared__ __align__(16) unsigned short Vs[128][72];   // V^T[dv][kv]
  __shared__ __align__(16) unsigned short Ps[4][16][72]; // per-wave P[q16][kv64]
  const int t = threadIdx.x, lane = t & 63, w = t >> 6;
  const int fr = lane & 15, fq = lane >> 4;
  const int qb = gridDim.x - 1 - blockIdx.x;  // heaviest blocks first
  const int q0 = qb * 128;
  const int bh = blockIdx.y;
  const unsigned short* Qb = Qp + (size_t)bh * Tt * DHd;
  const unsigned short* Kb = Kp + (size_t)bh * Tt * DHd;
  const unsigned short* Vb = Vt + (size_t)bh * DHd * Tt;

  bf16x8 qf[2][4];
#pragma unroll
  for (int mg = 0; mg < 2; ++mg)
#pragma unroll
    for (int ks = 0; ks < 4; ++ks)
      qf[mg][ks] = *(const bf16x8*)(Qb + (size_t)(q0 + w * 32 + mg * 16 + fr) * DHd +
                                    ks * 32 + fq * 8);

  f32x4 oacc[2][8] = {};
  float m_[2] = {-1e30f, -1e30f};
  float l_[2] = {0.f, 0.f};

  const int ntile = 2 * (qb + 1);
  for (int kt = 0; kt < ntile; ++kt) {
    const int kv0 = kt * 64;
    __syncthreads();  // protect K/V LDS vs previous tile's reads
    {
      const int rk = t >> 4, ck = (t & 15) * 8;
#pragma unroll
      for (int p = 0; p < 4; ++p)
        *(bf16x8*)&Ks[rk + 16 * p][ck] =
            *(const bf16x8*)(Kb + (size_t)(kv0 + rk + 16 * p) * DHd + ck);
      const int rv = t >> 3, cv = (t & 7) * 8;
#pragma unroll
      for (int p = 0; p < 4; ++p)
        *(bf16x8*)&Vs[rv + 32 * p][cv] =
            *(const bf16x8*)(Vb + (size_t)(rv + 32 * p) * Tt + kv0 + cv);
    }
    __syncthreads();

    const bool need_mask = (kt >= ntile - 2);
#pragma unroll
    for (int mg = 0; mg < 2; ++mg) {
      // S^T tile: lane holds S[kv = tt*16+fq*4+r][q = fr]
      f32x4 s[4] = {};
#pragma unroll
      for (int tt = 0; tt < 4; ++tt)
#pragma unroll
        for (int ks = 0; ks < 4; ++ks) {
          const bf16x8 kf = *(const bf16x8*)&Ks[tt * 16 + fr][ks * 32 + fq * 8];
          s[tt] = __builtin_amdgcn_mfma_f32_16x16x32_bf16(kf, qf[mg][ks], s[tt], 0, 0, 0);
        }
      const int qa = q0 + w * 32 + mg * 16 + fr;  // this lane's q-row
      if (need_mask) {
#pragma unroll
        for (int tt = 0; tt < 4; ++tt)
#pragma unroll
          for (int r = 0; r < 4; ++r)
            if (kv0 + tt * 16 + fq * 4 + r > qa) s[tt][r] = -1e30f;
      }
      // online softmax, per-lane scalar state (q = fr)
      float tmax = s[0][0];
#pragma unroll
      for (int tt = 0; tt < 4; ++tt)
#pragma unroll
        for (int r = 0; r < 4; ++r) tmax = fmaxf(tmax, s[tt][r]);
      tmax = fmaxf(tmax, __shfl_xor(tmax, 16));
      tmax = fmaxf(tmax, __shfl_xor(tmax, 32));
      const float mn = fmaxf(m_[mg], tmax);
      const float alpha = __expf(m_[mg] - mn);
      m_[mg] = mn;
      float rs = 0.f;
#pragma unroll
      for (int tt = 0; tt < 4; ++tt)
#pragma unroll
        for (int r = 0; r < 4; ++r) {
          const float p = __expf(s[tt][r] - mn);
          s[tt][r] = p;
          rs += p;
        }
      rs += __shfl_xor(rs, 16);
      rs += __shfl_xor(rs, 32);
      l_[mg] = l_[mg] * alpha + rs;
      // broadcast alpha from q=fr lanes to accumulator rows q=fq*4+r
      float al4[4];
#pragma unroll
      for (int r = 0; r < 4; ++r) al4[r] = __shfl(alpha, fq * 4 + r);
#pragma unroll
      for (int dt = 0; dt < 8; ++dt)
#pragma unroll
        for (int r = 0; r < 4; ++r) oacc[mg][dt][r] *= al4[r];
      // P^T -> Ps[q][kv], packed u16x4 (per-wave private: no barrier needed)
#pragma unroll
      for (int tt = 0; tt < 4; ++tt) {
        u16x4 pk;
#pragma unroll
        for (int r = 0; r < 4; ++r) pk[r] = f2bf(s[tt][r]);
        *(u16x4*)&Ps[w][fr][tt * 16 + fq * 4] = pk;
      }
      // PV: oacc[mg][dt] = out[q=fq*4+r][dv=dt*16+fr]
#pragma unroll
      for (int ks2 = 0; ks2 < 2; ++ks2) {
        const bf16x8 pf = *(const bf16x8*)&Ps[w][fr][ks2 * 32 + fq * 8];
#pragma unroll
        for (int dt = 0; dt < 8; ++dt) {
          const bf16x8 vf = *(const bf16x8*)&Vs[dt * 16 + fr][ks2 * 32 + fq * 8];
          oacc[mg][dt] = __builtin_amdgcn_mfma_f32_16x16x32_bf16(pf, vf, oacc[mg][dt], 0, 0, 0);
        }
      }
    }
  }

  const int bb = bh >> 4, hh = bh & 15;
#pragma unroll
  for (int mg = 0; mg < 2; ++mg) {
    float linv[4];
#pragma unroll
    for (int r = 0; r < 4; ++r) linv[r] = 1.0f / __shfl(l_[mg], fq * 4 + r);
    const int qrow = q0 + w * 32 + mg * 16 + fq * 4;
#pragma unroll
    for (int r = 0; r < 4; ++r) {
      unsigned short* o = Ao + ((size_t)bb * Tt + qrow + r) * Dd + hh * DHd + fr;
#pragma unroll
      for (int dt = 0; dt < 8; ++dt) o[dt * 16] = f2bf(oacc[mg][dt][r] * linv[r]);
    }
  }
}

// ---------------------------------------------------------------------------
extern "C" void kernel_launch(void* const* d_in, const int* in_sizes, int n_in,
                              void* d_out, int out_size, void* d_ws, size_t ws_size,
                              hipStream_t stream) {
  const float* q = (const float*)d_in[0];
  const float* k = (const float*)d_in[1];
  const float* v = (const float*)d_in[2];
  // d_in[3] = mask (known causal tril; unused)
  const float* Wq = (const float*)d_in[4];
  const float* Wk = (const float*)d_in[5];
  const float* Wv = (const float*)d_in[6];
  const float* Wo = (const float*)d_in[7];

  const size_t WE = (size_t)Dd * Dd;             // 4.19M elems
  const size_t PE = (size_t)Bb * Hh * Tt * DHd;  // 16.78M elems
  unsigned short* WqT = (unsigned short*)d_ws;
  unsigned short* WkT = WqT + WE;
  unsigned short* WvT = WkT + WE;
  unsigned short* WoT = WvT + WE;
  unsigned short* Qx = WoT + WE;  // [B,H,T,dh]
  unsigned short* Kx = Qx + PE;   // [B,H,T,dh]
  unsigned short* Vx = Kx + PE;   // [B,H,dh,T]
  unsigned short* Ax = Vx + PE;   // staging for bf16 q/k/v, then attn out [B,T,H*dh]

  wtrans_all<<<dim3(32, 32, 4), 256, 0, stream>>>(
      Wq, Wk, Wv, Wo, WqT, WkT, WvT, WoT, 0.088388347648318447f);

  cvt_bf16<<<dim3(8192), 256, 0, stream>>>(q, Ax);
  gemm_bt<1><<<dim3(64, 16), 256, 0, stream>>>(Ax, WqT, Qx);
  cvt_bf16<<<dim3(8192), 256, 0, stream>>>(k, Ax);
  gemm_bt<1><<<dim3(64, 16), 256, 0, stream>>>(Ax, WkT, Kx);
  cvt_bf16<<<dim3(8192), 256, 0, stream>>>(v, Ax);
  gemm_bt<2><<<dim3(64, 16), 256, 0, stream>>>(Ax, WvT, Vx);
  fattn<<<dim3(Tt / 128, Bb * Hh), 256, 0, stream>>>(Qx, Kx, Vx, Ax);
  gemm_bt<0><<<dim3(64, 16), 256, 0, stream>>>(Ax, WoT, (float*)d_out);
}